// Round 3
// baseline (190.843 us; speedup 1.0000x reference)
//
#include <hip/hip_runtime.h>

// SimpleRNN hidden=1: h_t = tanh(a*x_t + b*h_{t-1} + c), out = h_T per row.
// B=8192 rows x T=4096 steps, x fp32 [B,T] row-major.
//
// R9 = R8 with ONE change: staging loads are plain (cached) loads, not
// __builtin_nontemporal_load. A/B on the theory that the nt bit's
// L2-evict-first policy caps sustained read BW (~5.2 TB/s observed for the
// kernel vs 6.9 TB/s the same-graph fills sustain). Nothing else in the
// graph reuses L2, so dropping NT risks no pollution cost.
//
// Structure (R7/R8): one 256-thread block per row; thread t owns chunk t
// (256 chunks x 16 steps). Staging is WAVE-PRIVATE — wave w stages exactly
// the 4 KiB region it will read back (fx4 s in [256w, 256w+256)); the XOR
// swizzle phys = s ^ ((s>>2)&7) only touches bits 0..2 of s, so it never
// leaves a 256-fx4 region -> waves are fully independent in LDS and no
// staging __syncthreads() is needed (same-wave ds_write -> ds_read ordering
// comes from program order + lgkmcnt).
//
// Staging coalescing: s = w*256 + i*64 + lane -> 64 lanes x 16 B
// consecutive = 1 KiB per instruction, 4 instructions cover a contiguous
// 4 KiB span per wave.
//
// Swizzle conflict analysis (base w*256 + i*64 is 0 mod 8 in both (s&7)
// and ((s>>2)&7)):
//   write s = base+lane: quad = (lane&7)^((lane>>2)&7) -> 8 distinct / 8 lanes
//   read  s = 4t+q     : quad = (4(t&1)+q)^(t&7)       -> 8 distinct / 8 lanes
//
// Math (absmax 0.0 in all prior rounds): E = exp(2t); r = rcp(E+1);
//   h = 1-2r; E' = exp2(fma(r, nB4, q)), q = fma(x, A2, C2).
// Per chunk from h=0: G = chunk output, P = dF/dh|_0 = prod b*sech^2
// (post-step states; first pre-state factor skipped, final added at tail).
// Combine: affine maps compose associatively -> 6-step intra-wave shfl scan,
// then thread 0 composes the 4 wave totals (temporal order w=0..3).

constexpr int T_LEN = 4096;
constexpr int NTHR  = 256;
constexpr int CH    = T_LEN / NTHR;   // 16 steps per thread-chunk
constexpr int NF4   = CH / 4;         // 4 float4 per thread

typedef float fx4 __attribute__((ext_vector_type(4)));

__device__ __forceinline__ int swz(int s) { return s ^ ((s >> 2) & 7); }

#define STEP_PG(qv)                                                     \
    do {                                                                \
        float r_ = __builtin_amdgcn_rcpf(E + 1.0f);                     \
        P *= (fourb * r_) * (1.0f - r_);                                \
        E = __builtin_amdgcn_exp2f(fmaf(r_, nB4, (qv)));                \
    } while (0)

__global__ __launch_bounds__(NTHR)
void rnn_row_kernel(const float* __restrict__ x,
                    const float* __restrict__ w_ih,
                    const float* __restrict__ w_hh,
                    const float* __restrict__ b_ih,
                    const float* __restrict__ b_hh,
                    float* __restrict__ out) {
    __shared__ fx4 sm[T_LEN / 4];          // 16 KiB: one row
    __shared__ float wP[4], wG[4];         // per-wave affine totals

    const int tid  = threadIdx.x;
    const int lane = tid & 63;
    const int wv   = tid >> 6;
    const int row  = blockIdx.x;

    const float a  = w_ih[0];
    const float bb = w_hh[0];
    const float cc = b_ih[0] + b_hh[0];

    const float L2E2  = 2.88539008177792681472f;   // 2*log2(e)
    const float A2    = a * L2E2;
    const float C2    = (bb + cc) * L2E2;
    const float nB4   = -(bb * L2E2 * 2.0f);       // -4b*log2(e)
    const float fourb = 4.0f * bb;

    // --- Stage: wave-private, 4 coalesced dwordx4 per thread (NO nt) ---
    // Wave w covers fx4 indices [256w, 256w+256) = its own read region.
    const fx4* xp = (const fx4*)(x + (size_t)row * T_LEN);
#pragma unroll
    for (int i = 0; i < 4; ++i) {
        int s = (wv << 8) + (i << 6) + lane;
        sm[swz(s)] = xp[s];
    }
    // NO __syncthreads(): each wave reads back only LDS it wrote itself;
    // program order + lgkmcnt give the ordering within a wave.

    // --- Gather own 16-step chunk: 4 x ds_read_b128, 8-phase clean ---
    fx4 buf[NF4];
#pragma unroll
    for (int q = 0; q < NF4; ++q) buf[q] = sm[swz(tid * NF4 + q)];

    // --- 16-step chunk scan from h=0 with exact gain product ---
    float E, P = 1.0f;
    {
        fx4 v = buf[0];
        float q0 = fmaf(v.x, A2, C2);
        float q1 = fmaf(v.y, A2, C2);
        float q2 = fmaf(v.z, A2, C2);
        float q3 = fmaf(v.w, A2, C2);
        E = __builtin_amdgcn_exp2f(fmaf(0.5f, nB4, q0));  // h=0 => r=0.5 exact
        STEP_PG(q1); STEP_PG(q2); STEP_PG(q3);
    }
#pragma unroll
    for (int i = 1; i < NF4; ++i) {
        fx4 v = buf[i];
        float q0 = fmaf(v.x, A2, C2);
        float q1 = fmaf(v.y, A2, C2);
        float q2 = fmaf(v.z, A2, C2);
        float q3 = fmaf(v.w, A2, C2);
        STEP_PG(q0); STEP_PG(q1); STEP_PG(q2); STEP_PG(q3);
    }
    float r = __builtin_amdgcn_rcpf(E + 1.0f);
    float G = fmaf(-2.0f, r, 1.0f);
    P *= (fourb * r) * (1.0f - r);

    // --- Intra-wave inclusive affine scan (chunk order = lane order) ---
#pragma unroll
    for (int d = 1; d < 64; d <<= 1) {
        float Pl = __shfl_up(P, d, 64);
        float Gl = __shfl_up(G, d, 64);
        if (lane >= d) {
            G = fmaf(P, Gl, G);
            P *= Pl;
        }
    }
    if (lane == 63) { wP[wv] = P; wG[wv] = G; }
    __syncthreads();

    // --- Cross-wave composition, temporal order w=0..3; h0 = 0 ---
    if (tid == 0) {
        float h = wG[0];
        h = fmaf(wP[1], h, wG[1]);
        h = fmaf(wP[2], h, wG[2]);
        h = fmaf(wP[3], h, wG[3]);
        out[row] = h;
    }
}

extern "C" void kernel_launch(void* const* d_in, const int* in_sizes, int n_in,
                              void* d_out, int out_size, void* d_ws, size_t ws_size,
                              hipStream_t stream) {
    const float* x    = (const float*)d_in[0];
    const float* w_ih = (const float*)d_in[1];
    const float* w_hh = (const float*)d_in[2];
    const float* b_ih = (const float*)d_in[3];
    const float* b_hh = (const float*)d_in[4];
    float* out = (float*)d_out;

    const int B = out_size;                 // 8192 rows, one block per row
    dim3 grid(B), block(NTHR);
    rnn_row_kernel<<<grid, block, 0, stream>>>(x, w_ih, w_hh, b_ih, b_hh, out);
}

// Round 4
// 182.312 us; speedup vs baseline: 1.0468x; 1.0468x over previous
//
#include <hip/hip_runtime.h>

// SimpleRNN hidden=1: h_t = tanh(a*x_t + b*h_{t-1} + c), out = h_T per row.
// B=8192 rows x T=4096 steps, x fp32 [B,T] row-major.
//
// R10 = R8 (NT loads RESTORED — R9 proved dropping nt costs ~10 us of L2
// thrash) + persistent 4-rows-per-block with register prefetch:
//   grid = B/4 = 2048 blocks = exactly 8 resident per CU. Each block scans
//   4 consecutive rows; each wave NT-prefetches row r+1's private 4 KiB
//   into 16 VGPRs BEFORE computing row r, so the memory pipe stays fed
//   across row boundaries and 3/4 of block-launch ramp gaps vanish.
// Per-row barrier eliminated: wave totals go to wPG[r][wv] (each slot
// written exactly once), ONE __syncthreads() at block end, then tids 0..3
// combine one row each (coalesced 4-float out write).
//
// Wave-private staging (from R7/R8): wave w stages exactly the 4 KiB
// region it reads back (fx4 s in [256w,256w+256)); swizzle
// phys = s ^ ((s>>2)&7) touches only bits 0..2, never leaves the region
// -> no staging barrier. ds_write(row r+1) after ds_read(row r) is safe:
// same wave, program order, may-alias -> compiler keeps the order.
//
// Swizzle conflict analysis (base w*256+i*64 is 0 mod 8 in (s&7),((s>>2)&7)):
//   write s=base+lane: quad = (lane&7)^((lane>>2)&7) -> 8 distinct / 8 lanes
//   read  s=4t+q     : quad = (4(t&1)+q)^(t&7)       -> 8 distinct / 8 lanes
//
// Math (absmax 0.0 all rounds): E = exp(2t); r = rcp(E+1); h = 1-2r;
//   E' = exp2(fma(r, nB4, q)), q = fma(x, A2, C2).
// Per chunk from h=0: G = chunk output, P = prod b*sech^2 (post-step
// states; first pre-state factor skipped, final added at tail).
// Affine maps compose -> 6-step intra-wave shfl scan, then per-row
// cross-wave composition in temporal order w=0..3.

constexpr int T_LEN = 4096;
constexpr int NTHR  = 256;
constexpr int CH    = T_LEN / NTHR;   // 16 steps per thread-chunk
constexpr int NF4   = CH / 4;         // 4 float4 per thread
constexpr int RPB   = 4;              // rows per block

typedef float fx4 __attribute__((ext_vector_type(4)));

__device__ __forceinline__ int swz(int s) { return s ^ ((s >> 2) & 7); }

#define STEP_PG(qv)                                                     \
    do {                                                                \
        float r_ = __builtin_amdgcn_rcpf(E + 1.0f);                     \
        P *= (fourb * r_) * (1.0f - r_);                                \
        E = __builtin_amdgcn_exp2f(fmaf(r_, nB4, (qv)));                \
    } while (0)

__global__ __launch_bounds__(NTHR, 8)
void rnn_row_kernel(const float* __restrict__ x,
                    const float* __restrict__ w_ih,
                    const float* __restrict__ w_hh,
                    const float* __restrict__ b_ih,
                    const float* __restrict__ b_hh,
                    float* __restrict__ out) {
    __shared__ fx4 sm[T_LEN / 4];          // 16 KiB: one row
    __shared__ float wP4[RPB][4], wG4[RPB][4];  // per-row per-wave totals

    const int tid  = threadIdx.x;
    const int lane = tid & 63;
    const int wv   = tid >> 6;
    const int row0 = blockIdx.x * RPB;

    const float a  = w_ih[0];
    const float bb = w_hh[0];
    const float cc = b_ih[0] + b_hh[0];

    const float L2E2  = 2.88539008177792681472f;   // 2*log2(e)
    const float A2    = a * L2E2;
    const float C2    = (bb + cc) * L2E2;
    const float nB4   = -(bb * L2E2 * 2.0f);       // -4b*log2(e)
    const float fourb = 4.0f * bb;

    // --- Prefetch row 0 into regs (wave-private 4 KiB, NT, coalesced) ---
    fx4 pf[NF4];
    {
        const fx4* xp = (const fx4*)(x + (size_t)row0 * T_LEN);
#pragma unroll
        for (int i = 0; i < NF4; ++i) {
            int s = (wv << 8) + (i << 6) + lane;
            pf[i] = __builtin_nontemporal_load(&xp[s]);
        }
    }

#pragma unroll
    for (int r = 0; r < RPB; ++r) {
        // Commit prefetched row r to swizzled LDS (wave-private region).
        // WAR on pf regs orders this before the next prefetch below.
#pragma unroll
        for (int i = 0; i < NF4; ++i) {
            int s = (wv << 8) + (i << 6) + lane;
            sm[swz(s)] = pf[i];
        }
        // Issue NT prefetch of row r+1 now; it flies during the compute.
        if (r + 1 < RPB) {
            const fx4* xn = (const fx4*)(x + (size_t)(row0 + r + 1) * T_LEN);
#pragma unroll
            for (int i = 0; i < NF4; ++i) {
                int s = (wv << 8) + (i << 6) + lane;
                pf[i] = __builtin_nontemporal_load(&xn[s]);
            }
        }

        // Gather own 16-step chunk: 4 x ds_read_b128, 8-phase clean.
        fx4 buf[NF4];
#pragma unroll
        for (int q = 0; q < NF4; ++q) buf[q] = sm[swz(tid * NF4 + q)];

        // 16-step chunk scan from h=0 with exact gain product.
        float E, P = 1.0f;
        {
            fx4 v = buf[0];
            float q0 = fmaf(v.x, A2, C2);
            float q1 = fmaf(v.y, A2, C2);
            float q2 = fmaf(v.z, A2, C2);
            float q3 = fmaf(v.w, A2, C2);
            E = __builtin_amdgcn_exp2f(fmaf(0.5f, nB4, q0));  // h=0 => r=0.5
            STEP_PG(q1); STEP_PG(q2); STEP_PG(q3);
        }
#pragma unroll
        for (int i = 1; i < NF4; ++i) {
            fx4 v = buf[i];
            float q0 = fmaf(v.x, A2, C2);
            float q1 = fmaf(v.y, A2, C2);
            float q2 = fmaf(v.z, A2, C2);
            float q3 = fmaf(v.w, A2, C2);
            STEP_PG(q0); STEP_PG(q1); STEP_PG(q2); STEP_PG(q3);
        }
        float rr = __builtin_amdgcn_rcpf(E + 1.0f);
        float G = fmaf(-2.0f, rr, 1.0f);
        P *= (fourb * rr) * (1.0f - rr);

        // Intra-wave inclusive affine scan (chunk order = lane order).
#pragma unroll
        for (int d = 1; d < 64; d <<= 1) {
            float Pl = __shfl_up(P, d, 64);
            float Gl = __shfl_up(G, d, 64);
            if (lane >= d) {
                G = fmaf(P, Gl, G);
                P *= Pl;
            }
        }
        if (lane == 63) { wP4[r][wv] = P; wG4[r][wv] = G; }
        // No barrier here: each wPG slot is written once, read only after
        // the single block-end barrier below.
    }

    __syncthreads();

    // --- Cross-wave composition per row, temporal order w=0..3; h0=0 ---
    if (tid < RPB) {
        float h = wG4[tid][0];
        h = fmaf(wP4[tid][1], h, wG4[tid][1]);
        h = fmaf(wP4[tid][2], h, wG4[tid][2]);
        h = fmaf(wP4[tid][3], h, wG4[tid][3]);
        out[row0 + tid] = h;
    }
}

extern "C" void kernel_launch(void* const* d_in, const int* in_sizes, int n_in,
                              void* d_out, int out_size, void* d_ws, size_t ws_size,
                              hipStream_t stream) {
    const float* x    = (const float*)d_in[0];
    const float* w_ih = (const float*)d_in[1];
    const float* w_hh = (const float*)d_in[2];
    const float* b_ih = (const float*)d_in[3];
    const float* b_hh = (const float*)d_in[4];
    float* out = (float*)d_out;

    const int B = out_size;                 // 8192 rows
    dim3 grid(B / RPB), block(NTHR);        // 2048 blocks = 8 per CU
    rnn_row_kernel<<<grid, block, 0, stream>>>(x, w_ih, w_hh, b_ih, b_hh, out);
}